// Round 15
// baseline (141.717 us; speedup 1.0000x reference)
//
#include <hip/hip_runtime.h>

// Exact-match lookup of 4M int32 queries in a sorted 8M int32 key table.
// Round 15: round-12 pipeline (index -> fused rank-scatter build+bitmap ->
// bitmap-filtered packed lookup, 4 probe chains/thread) with a slimmer build:
//   - stage KEYS only in LDS; vals read direct from global (coalesced, once)
//   - single main pass: rank via <=5-element LDS lookback (sorted keys =>
//     rank = # consecutive same-bucket predecessors); bucket-first index is
//     only needed for overflow descriptors and every flag-setter writes the
//     identical value (benign multi-writer)
//   - one fewer __syncthreads, ~40% less LDS traffic, 10.1 KB LDS/block
//
// Table: B = 2^23 buckets (bucket = (unsigned)key >> 8), 16 B/bucket = 128 MB.
// Entry = 4 x 32-bit slots; keys in a bucket share bits [30:8]:
//   bits[31:28] flags: 0=empty, 1=valid pair, 2=overflow descriptor (word0)
//   bits[27:8]  value (build verifies 0 <= val < 2^20, else overflow)
//   bits[7:0]   low 8 bits of key
// Overflow (count>4 or value out of range): word0 = 2<<28, word1 = start
// index into keys/vals; lookup scans forward with early exit on key >= q.
// Slots filled in sorted order, checked in order -> searchsorted-left.
// Queries are >= 1 so empty slots (0) never false-match.
//
// Bitmap: bit b = "some key has key>>7 == b" (2^24 bits = 2 MB). Bit clear ->
// query absent -> skip the table probe (~61% of misses skip). Built with LDS
// atomicOr (commutative -> deterministic) + one 64B line store per block.

constexpr int WCAP     = 1024;     // LDS window capacity per 256-bucket block
constexpr int NBLK     = 1 << 15;  // 32768 build blocks (256 buckets each)
constexpr int BM_WORDS = 1 << 19;  // 2^24 bits / 32 = 512K words = 2 MB

typedef int vint4 __attribute__((ext_vector_type(4)));

__device__ __forceinline__ int lower_bound_u(const int* __restrict__ keys,
                                             int lo, int hi, unsigned t) {
    while (lo < hi) {
        int m = (lo + hi) >> 1;
        if ((unsigned)keys[m] < t) lo = m + 1; else hi = m;
    }
    return lo;
}

// K1: bstart[i] = lower_bound(keys, (i*256)<<8), i in [0, NBLK] inclusive.
__global__ void block_index_kernel(const int* __restrict__ keys, int K,
                                   int* __restrict__ bstart) {
    int i = blockIdx.x * blockDim.x + threadIdx.x;
    if (i > NBLK) return;
    bstart[i] = lower_bound_u(keys, 0, K, ((unsigned)i) << 16);
}

// K2: single-pass rank-scatter build + fused bitmap.
// One block = 256 buckets = 16 bitmap words (one 64B bitmap line per block).
__global__ void __launch_bounds__(256) build_rank_kernel(
        const int* __restrict__ keys, const int* __restrict__ vals, int K,
        const int* __restrict__ bstart, int4* __restrict__ table,
        unsigned* __restrict__ bitmap) {
    __shared__ int s_keys[WCAP];
    __shared__ int s_first[256];
    __shared__ int s_flag[256];
    __shared__ int s_ent[256][4];
    __shared__ unsigned s_bm[16];

    const int tid = threadIdx.x;
    const int wlo = bstart[blockIdx.x];
    const int whi = bstart[blockIdx.x + 1];
    const int wn = whi - wlo;
    const unsigned base_b = (unsigned)blockIdx.x << 8;

    s_flag[tid] = 0;
    s_ent[tid][0] = 0; s_ent[tid][1] = 0; s_ent[tid][2] = 0; s_ent[tid][3] = 0;
    if (tid < 16) s_bm[tid] = 0u;

    if (wn <= WCAP) {
        for (int j = tid; j < wn; j += 256) s_keys[j] = keys[wlo + j];
        __syncthreads();

        // main pass: rank via lookback; vals direct from global (coalesced).
        for (int j = tid; j < wn; j += 256) {
            unsigned k = (unsigned)s_keys[j];
            unsigned kb = k >> 8;
            unsigned lb = kb & 255u;
            // rank = # consecutive same-bucket predecessors, capped at 4
            int r = 0;
            while (r < 4 && j - 1 - r >= 0 &&
                   (((unsigned)s_keys[j - 1 - r]) >> 8) == kb) ++r;
            if (r < 4) {
                int v = vals[wlo + j];
                if ((unsigned)v <= 0xFFFFFu) {
                    s_ent[lb][r] = (1 << 28) | (v << 8) | ((int)k & 0xFF);
                } else {
                    s_flag[lb] = 1;
                    s_first[lb] = j - r;  // bucket first (same value from any writer)
                }
            } else {
                // rank >= 4 -> overflow bucket
                s_flag[lb] = 1;
                bool exact4 = (j - 5 < 0) ||
                              ((((unsigned)s_keys[j - 5]) >> 8) != kb);
                if (exact4) s_first[lb] = j - 4;  // unique rank-4 key
            }
            atomicOr(&s_bm[(k >> 12) & 15u], 1u << ((k >> 7) & 31u));
        }
        __syncthreads();

        // emit: table slice (coalesced 16B stores) + bitmap line
        int4 e;
        if (s_flag[tid]) e = make_int4(2 << 28, wlo + s_first[tid], 0, 0);
        else             e = make_int4(s_ent[tid][0], s_ent[tid][1],
                                       s_ent[tid][2], s_ent[tid][3]);
        table[base_b + tid] = e;
        if (tid < 16) bitmap[(unsigned)blockIdx.x * 16u + tid] = s_bm[tid];
    } else {
        // statistically-never fallback: window too big for LDS.
        __syncthreads();
        unsigned b = base_b + tid;
        unsigned tlo = b << 8;
        unsigned thi = tlo + 256u;
        int lo = lower_bound_u(keys, wlo, whi, tlo);
        int w[4] = {0, 0, 0, 0};
        bool ok = true;
        int cnt = 0;
        int j = lo;
        while (j < whi && (unsigned)keys[j] < thi) {
            if (cnt >= 4) { ok = false; break; }
            int v = vals[j];
            if ((unsigned)v > 0xFFFFFu) { ok = false; break; }
            w[cnt] = (1 << 28) | (v << 8) | (keys[j] & 0xFF);
            ++cnt; ++j;
        }
        table[b] = ok ? make_int4(w[0], w[1], w[2], w[3])
                      : make_int4(2 << 28, lo, 0, 0);
        if (tid < 16) {  // bitmap words from global window (correct, slow)
            unsigned w0 = (unsigned)blockIdx.x * 16u + tid;
            unsigned t0 = w0 << 12, t1 = t0 + 4096u;
            int l = lower_bound_u(keys, wlo, whi, t0);
            unsigned word = 0;
            for (int jj = l; jj < whi; ++jj) {
                unsigned k = (unsigned)keys[jj];
                if (k >= t1) break;
                word |= 1u << ((k >> 7) & 31u);
            }
            bitmap[w0] = word;
        }
    }
}

__device__ __forceinline__ int resolve_packed(int q, int4 e,
                                              const int* __restrict__ keys,
                                              const int* __restrict__ vals,
                                              int K) {
    if ((((unsigned)e.x) >> 28) == 2u) {  // overflow: scan original arrays
        for (int j = e.y; j < K; ++j) {
            int k = keys[j];
            if ((unsigned)k >= (unsigned)q) return (k == q) ? vals[j] : -1;
        }
        return -1;
    }
    int ql = q & 0xFF;
    int w;
    w = e.x; if ((((unsigned)w) >> 28) == 1u && (w & 0xFF) == ql) return (w >> 8) & 0xFFFFF;
    w = e.y; if ((((unsigned)w) >> 28) == 1u && (w & 0xFF) == ql) return (w >> 8) & 0xFFFFF;
    w = e.z; if ((((unsigned)w) >> 28) == 1u && (w & 0xFF) == ql) return (w >> 8) & 0xFFFFF;
    w = e.w; if ((((unsigned)w) >> 28) == 1u && (w & 0xFF) == ql) return (w >> 8) & 0xFFFFF;
    return -1;
}

// K3: bitmap-filtered lookup — 4 independent probe chains per thread.
// query/out nt (pure streams); table/bitmap cached (L2/L3 resident).
__global__ void lookup_bm_kernel(const int* __restrict__ query,
                                 const int* __restrict__ keys,
                                 const int* __restrict__ vals,
                                 const int4* __restrict__ table,
                                 const unsigned* __restrict__ bitmap,
                                 int* __restrict__ out,
                                 int N, int K, unsigned Bmask) {
    int nq4 = N >> 2;  // full 4-query groups
    int i = blockIdx.x * blockDim.x + threadIdx.x;
    if (i < nq4) {
        vint4 qv = __builtin_nontemporal_load(
            reinterpret_cast<const vint4*>(query) + i);
        int q[4] = {qv.x, qv.y, qv.z, qv.w};
        unsigned wbits[4];
#pragma unroll
        for (int c = 0; c < 4; ++c) wbits[c] = bitmap[((unsigned)q[c]) >> 12];
        bool probe[4];
        int4 e[4];
#pragma unroll
        for (int c = 0; c < 4; ++c) {
            probe[c] = ((wbits[c] >> ((((unsigned)q[c]) >> 7) & 31u)) & 1u) != 0u;
            e[c] = probe[c] ? table[(((unsigned)q[c]) >> 8) & Bmask]
                            : make_int4(0, 0, 0, 0);
        }
        vint4 r;
        r.x = probe[0] ? resolve_packed(q[0], e[0], keys, vals, K) : -1;
        r.y = probe[1] ? resolve_packed(q[1], e[1], keys, vals, K) : -1;
        r.z = probe[2] ? resolve_packed(q[2], e[2], keys, vals, K) : -1;
        r.w = probe[3] ? resolve_packed(q[3], e[3], keys, vals, K) : -1;
        __builtin_nontemporal_store(r, reinterpret_cast<vint4*>(out) + i);
    } else if (i == nq4) {
        // tail (N % 4 queries), single thread, plain cached path
        for (int j = nq4 * 4; j < N; ++j) {
            int q = query[j];
            unsigned wb = bitmap[((unsigned)q) >> 12];
            bool probe = ((wb >> ((((unsigned)q) >> 7) & 31u)) & 1u) != 0u;
            int r = -1;
            if (probe) {
                int4 e = table[(((unsigned)q) >> 8) & Bmask];
                r = resolve_packed(q, e, keys, vals, K);
            }
            out[j] = r;
        }
    }
}

// K3 alt: no-bitmap lookup (2 probe chains) for smaller workspaces.
__global__ void lookup_packed_kernel(const int* __restrict__ query,
                                     const int* __restrict__ keys,
                                     const int* __restrict__ vals,
                                     const int4* __restrict__ table,
                                     int* __restrict__ out,
                                     int N, int K, unsigned Bmask) {
    int half = (N + 1) >> 1;
    int i = blockIdx.x * blockDim.x + threadIdx.x;
    if (i >= half) return;
    int i1 = i + half;
    bool has1 = (i1 < N);
    int q0 = query[i];
    int q1 = has1 ? query[i1] : q0;
    int4 e0 = table[(((unsigned)q0) >> 8) & Bmask];
    int4 e1 = table[(((unsigned)q1) >> 8) & Bmask];
    out[i] = resolve_packed(q0, e0, keys, vals, K);
    if (has1) out[i1] = resolve_packed(q1, e1, keys, vals, K);
}

// Fallback for tiny workspace: plain binary search (searchsorted 'left').
__global__ void lookup_bsearch_kernel(const int* __restrict__ query,
                                      const int* __restrict__ keys,
                                      const int* __restrict__ vals,
                                      int* __restrict__ out,
                                      int N, int K) {
    int i = blockIdx.x * blockDim.x + threadIdx.x;
    if (i >= N) return;
    unsigned q = (unsigned)query[i];
    int lo = lower_bound_u(keys, 0, K, q);
    int r = -1;
    if (lo < K && (unsigned)keys[lo] == q) r = vals[lo];
    out[i] = r;
}

extern "C" void kernel_launch(void* const* d_in, const int* in_sizes, int n_in,
                              void* d_out, int out_size, void* d_ws, size_t ws_size,
                              hipStream_t stream) {
    const int* query = (const int*)d_in[0];
    const int* keys  = (const int*)d_in[1];
    const int* vals  = (const int*)d_in[2];
    int* out = (int*)d_out;
    const int N = in_sizes[0];
    const int K = in_sizes[1];
    const int tb = 256;

    const size_t TABLE_BYTES = (size_t)16 << 23;                     // 128 MB
    const size_t IDX_BYTES   = (((size_t)(NBLK + 1) * 4) + 63) & ~(size_t)63;
    const size_t BM_BYTES    = (size_t)BM_WORDS * 4;                 // 2 MB

    if (TABLE_BYTES + IDX_BYTES + BM_BYTES <= ws_size) {
        const unsigned B = 1u << 23;
        int4* table = (int4*)d_ws;
        int* bstart = (int*)((char*)d_ws + TABLE_BYTES);
        unsigned* bitmap = (unsigned*)((char*)d_ws + TABLE_BYTES + IDX_BYTES);
        block_index_kernel<<<(NBLK + 1 + tb - 1) / tb, tb, 0, stream>>>(keys, K, bstart);
        build_rank_kernel<<<NBLK, tb, 0, stream>>>(keys, vals, K, bstart, table,
                                                   bitmap);
        int nthreads = (N >> 2) + 1;  // 4-query groups + tail thread
        lookup_bm_kernel<<<(nthreads + tb - 1) / tb, tb, 0, stream>>>(
            query, keys, vals, table, bitmap, out, N, K, B - 1);
    } else if (TABLE_BYTES <= ws_size) {
        const unsigned B = 1u << 23;
        int4* table = (int4*)d_ws;
        int* bstart = (TABLE_BYTES + (size_t)(NBLK + 1) * 4 <= ws_size)
                          ? (int*)((char*)d_ws + TABLE_BYTES)
                          : (int*)d_out;  // legal scratch: lookup overwrites out
        unsigned* bitmap = (unsigned*)d_out;  // scratch; lookup overwrites out
        block_index_kernel<<<(NBLK + 1 + tb - 1) / tb, tb, 0, stream>>>(keys, K, bstart);
        build_rank_kernel<<<NBLK, tb, 0, stream>>>(keys, vals, K, bstart, table,
                                                   bitmap);
        int half = (N + 1) >> 1;
        lookup_packed_kernel<<<(half + tb - 1) / tb, tb, 0, stream>>>(
            query, keys, vals, table, out, N, K, B - 1);
    } else {
        lookup_bsearch_kernel<<<(N + tb - 1) / tb, tb, 0, stream>>>(query, keys,
                                                                    vals, out, N, K);
    }
}

// Round 16
// 138.533 us; speedup vs baseline: 1.0230x; 1.0230x over previous
//
#include <hip/hip_runtime.h>

// Exact-match lookup of 4M int32 queries in a sorted 8M int32 key table.
// Round 16: exact round-12 pipeline (best passing, 134.4 us): index -> fused
// 4-pass rank-scatter build+bitmap -> bitmap-filtered packed lookup (4 probe
// chains/thread). One delta: the build's table/bitmap emissions use
// NON-TEMPORAL STORES (single-touch write streams; no L2 allocation; the
// dispatch-boundary release publishes them to L3 for the lookup's cached
// reads -- no round-13-style bypass-READ hazard).
//
// Table: B = 2^23 buckets (bucket = (unsigned)key >> 8), 16 B/bucket = 128 MB.
// Entry = 4 x 32-bit slots; keys in a bucket share bits [30:8]:
//   bits[31:28] flags: 0=empty, 1=valid pair, 2=overflow descriptor (word0)
//   bits[27:8]  value (build verifies 0 <= val < 2^20, else overflow)
//   bits[7:0]   low 8 bits of key
// Overflow (count>4 or value out of range): word0 = 2<<28, word1 = start
// index into keys/vals; lookup scans forward with early exit on key >= q.
// Slots filled in sorted order, checked in order -> searchsorted-left.
// Queries are >= 1 so empty slots (0) never false-match.
//
// Bitmap: bit b = "some key has key>>7 == b" (2^24 bits = 2 MB). Bit clear ->
// query absent -> skip the table probe (~61% of misses skip). Built with LDS
// atomicOr (commutative -> deterministic) + one 64B line store per block.

constexpr int WCAP     = 1024;     // LDS window capacity per 256-bucket block
constexpr int NBLK     = 1 << 15;  // 32768 build blocks (256 buckets each)
constexpr int BM_WORDS = 1 << 19;  // 2^24 bits / 32 = 512K words = 2 MB

typedef int vint4 __attribute__((ext_vector_type(4)));

__device__ __forceinline__ int lower_bound_u(const int* __restrict__ keys,
                                             int lo, int hi, unsigned t) {
    while (lo < hi) {
        int m = (lo + hi) >> 1;
        if ((unsigned)keys[m] < t) lo = m + 1; else hi = m;
    }
    return lo;
}

// K1: bstart[i] = lower_bound(keys, (i*256)<<8), i in [0, NBLK] inclusive.
__global__ void block_index_kernel(const int* __restrict__ keys, int K,
                                   int* __restrict__ bstart) {
    int i = blockIdx.x * blockDim.x + threadIdx.x;
    if (i > NBLK) return;
    bstart[i] = lower_bound_u(keys, 0, K, ((unsigned)i) << 16);
}

// K2: 4-pass rank-scatter build + fused bitmap (round-12 structure).
// One block = 256 buckets = 16 bitmap words (one 64B bitmap line per block).
__global__ void __launch_bounds__(256) build_rank_kernel(
        const int* __restrict__ keys, const int* __restrict__ vals, int K,
        const int* __restrict__ bstart, int4* __restrict__ table,
        unsigned* __restrict__ bitmap) {
    __shared__ int s_keys[WCAP];
    __shared__ int s_vals[WCAP];
    __shared__ int s_first[256];
    __shared__ int s_flag[256];
    __shared__ int s_ent[256][4];
    __shared__ unsigned s_bm[16];

    const int tid = threadIdx.x;
    const int wlo = bstart[blockIdx.x];
    const int whi = bstart[blockIdx.x + 1];
    const int wn = whi - wlo;
    const unsigned base_b = (unsigned)blockIdx.x << 8;

    s_flag[tid] = 0;
    s_ent[tid][0] = 0; s_ent[tid][1] = 0; s_ent[tid][2] = 0; s_ent[tid][3] = 0;
    if (tid < 16) s_bm[tid] = 0u;

    if (wn <= WCAP) {
        for (int j = tid; j < wn; j += 256) {
            s_keys[j] = keys[wlo + j];
            s_vals[j] = vals[wlo + j];
        }
        __syncthreads();
        // pass B: bucket-first marks (unique writer) + bitmap bits (atomicOr)
        for (int j = tid; j < wn; j += 256) {
            unsigned k = (unsigned)s_keys[j];
            unsigned b = k >> 8;
            bool first = (j == 0) || ((((unsigned)s_keys[j - 1]) >> 8) != b);
            if (first) s_first[b & 255u] = j;
            atomicOr(&s_bm[(k >> 12) & 15u], 1u << ((k >> 7) & 31u));
        }
        __syncthreads();
        // pass C: rank-scatter packed words (unique (bucket,rank) writer)
        for (int j = tid; j < wn; j += 256) {
            int k = s_keys[j];
            unsigned lb = (((unsigned)k) >> 8) & 255u;
            int rank = j - s_first[lb];
            int v = s_vals[j];
            if (rank < 4 && (unsigned)v <= 0xFFFFFu) {
                s_ent[lb][rank] = (1 << 28) | (v << 8) | (k & 0xFF);
            } else {
                s_flag[lb] = 1;  // benign same-value multi-writer
            }
        }
        __syncthreads();
        // pass D: emit table slice + bitmap line with NT stores (single-touch
        // write streams; no L2 allocation; visible to next dispatch via L3).
        vint4 e;
        if (s_flag[tid]) { e.x = 2 << 28; e.y = wlo + s_first[tid]; e.z = 0; e.w = 0; }
        else { e.x = s_ent[tid][0]; e.y = s_ent[tid][1];
               e.z = s_ent[tid][2]; e.w = s_ent[tid][3]; }
        __builtin_nontemporal_store(
            e, reinterpret_cast<vint4*>(table) + (base_b + tid));
        if (tid < 16)
            __builtin_nontemporal_store(
                s_bm[tid], bitmap + ((unsigned)blockIdx.x * 16u + tid));
    } else {
        // statistically-never fallback: window too big for LDS.
        __syncthreads();
        unsigned b = base_b + tid;
        unsigned tlo = b << 8;
        unsigned thi = tlo + 256u;
        int lo = lower_bound_u(keys, wlo, whi, tlo);
        int w[4] = {0, 0, 0, 0};
        bool ok = true;
        int cnt = 0;
        int j = lo;
        while (j < whi && (unsigned)keys[j] < thi) {
            if (cnt >= 4) { ok = false; break; }
            int v = vals[j];
            if ((unsigned)v > 0xFFFFFu) { ok = false; break; }
            w[cnt] = (1 << 28) | (v << 8) | (keys[j] & 0xFF);
            ++cnt; ++j;
        }
        table[b] = ok ? make_int4(w[0], w[1], w[2], w[3])
                      : make_int4(2 << 28, lo, 0, 0);
        if (tid < 16) {  // bitmap words from global window (correct, slow)
            unsigned w0 = (unsigned)blockIdx.x * 16u + tid;
            unsigned t0 = w0 << 12, t1 = t0 + 4096u;
            int l = lower_bound_u(keys, wlo, whi, t0);
            unsigned word = 0;
            for (int jj = l; jj < whi; ++jj) {
                unsigned k = (unsigned)keys[jj];
                if (k >= t1) break;
                word |= 1u << ((k >> 7) & 31u);
            }
            bitmap[w0] = word;
        }
    }
}

__device__ __forceinline__ int resolve_packed(int q, int4 e,
                                              const int* __restrict__ keys,
                                              const int* __restrict__ vals,
                                              int K) {
    if ((((unsigned)e.x) >> 28) == 2u) {  // overflow: scan original arrays
        for (int j = e.y; j < K; ++j) {
            int k = keys[j];
            if ((unsigned)k >= (unsigned)q) return (k == q) ? vals[j] : -1;
        }
        return -1;
    }
    int ql = q & 0xFF;
    int w;
    w = e.x; if ((((unsigned)w) >> 28) == 1u && (w & 0xFF) == ql) return (w >> 8) & 0xFFFFF;
    w = e.y; if ((((unsigned)w) >> 28) == 1u && (w & 0xFF) == ql) return (w >> 8) & 0xFFFFF;
    w = e.z; if ((((unsigned)w) >> 28) == 1u && (w & 0xFF) == ql) return (w >> 8) & 0xFFFFF;
    w = e.w; if ((((unsigned)w) >> 28) == 1u && (w & 0xFF) == ql) return (w >> 8) & 0xFFFFF;
    return -1;
}

// K3: bitmap-filtered lookup — 4 independent probe chains per thread.
// query/out nt (pure streams); table/bitmap cached (L2/L3 resident).
__global__ void lookup_bm_kernel(const int* __restrict__ query,
                                 const int* __restrict__ keys,
                                 const int* __restrict__ vals,
                                 const int4* __restrict__ table,
                                 const unsigned* __restrict__ bitmap,
                                 int* __restrict__ out,
                                 int N, int K, unsigned Bmask) {
    int nq4 = N >> 2;  // full 4-query groups
    int i = blockIdx.x * blockDim.x + threadIdx.x;
    if (i < nq4) {
        vint4 qv = __builtin_nontemporal_load(
            reinterpret_cast<const vint4*>(query) + i);
        int q[4] = {qv.x, qv.y, qv.z, qv.w};
        unsigned wbits[4];
#pragma unroll
        for (int c = 0; c < 4; ++c) wbits[c] = bitmap[((unsigned)q[c]) >> 12];
        bool probe[4];
        int4 e[4];
#pragma unroll
        for (int c = 0; c < 4; ++c) {
            probe[c] = ((wbits[c] >> ((((unsigned)q[c]) >> 7) & 31u)) & 1u) != 0u;
            e[c] = probe[c] ? table[(((unsigned)q[c]) >> 8) & Bmask]
                            : make_int4(0, 0, 0, 0);
        }
        vint4 r;
        r.x = probe[0] ? resolve_packed(q[0], e[0], keys, vals, K) : -1;
        r.y = probe[1] ? resolve_packed(q[1], e[1], keys, vals, K) : -1;
        r.z = probe[2] ? resolve_packed(q[2], e[2], keys, vals, K) : -1;
        r.w = probe[3] ? resolve_packed(q[3], e[3], keys, vals, K) : -1;
        __builtin_nontemporal_store(r, reinterpret_cast<vint4*>(out) + i);
    } else if (i == nq4) {
        // tail (N % 4 queries), single thread, plain cached path
        for (int j = nq4 * 4; j < N; ++j) {
            int q = query[j];
            unsigned wb = bitmap[((unsigned)q) >> 12];
            bool probe = ((wb >> ((((unsigned)q) >> 7) & 31u)) & 1u) != 0u;
            int r = -1;
            if (probe) {
                int4 e = table[(((unsigned)q) >> 8) & Bmask];
                r = resolve_packed(q, e, keys, vals, K);
            }
            out[j] = r;
        }
    }
}

// K3 alt: no-bitmap lookup (2 probe chains) for smaller workspaces.
__global__ void lookup_packed_kernel(const int* __restrict__ query,
                                     const int* __restrict__ keys,
                                     const int* __restrict__ vals,
                                     const int4* __restrict__ table,
                                     int* __restrict__ out,
                                     int N, int K, unsigned Bmask) {
    int half = (N + 1) >> 1;
    int i = blockIdx.x * blockDim.x + threadIdx.x;
    if (i >= half) return;
    int i1 = i + half;
    bool has1 = (i1 < N);
    int q0 = query[i];
    int q1 = has1 ? query[i1] : q0;
    int4 e0 = table[(((unsigned)q0) >> 8) & Bmask];
    int4 e1 = table[(((unsigned)q1) >> 8) & Bmask];
    out[i] = resolve_packed(q0, e0, keys, vals, K);
    if (has1) out[i1] = resolve_packed(q1, e1, keys, vals, K);
}

// Fallback for tiny workspace: plain binary search (searchsorted 'left').
__global__ void lookup_bsearch_kernel(const int* __restrict__ query,
                                      const int* __restrict__ keys,
                                      const int* __restrict__ vals,
                                      int* __restrict__ out,
                                      int N, int K) {
    int i = blockIdx.x * blockDim.x + threadIdx.x;
    if (i >= N) return;
    unsigned q = (unsigned)query[i];
    int lo = lower_bound_u(keys, 0, K, q);
    int r = -1;
    if (lo < K && (unsigned)keys[lo] == q) r = vals[lo];
    out[i] = r;
}

extern "C" void kernel_launch(void* const* d_in, const int* in_sizes, int n_in,
                              void* d_out, int out_size, void* d_ws, size_t ws_size,
                              hipStream_t stream) {
    const int* query = (const int*)d_in[0];
    const int* keys  = (const int*)d_in[1];
    const int* vals  = (const int*)d_in[2];
    int* out = (int*)d_out;
    const int N = in_sizes[0];
    const int K = in_sizes[1];
    const int tb = 256;

    const size_t TABLE_BYTES = (size_t)16 << 23;                     // 128 MB
    const size_t IDX_BYTES   = (((size_t)(NBLK + 1) * 4) + 63) & ~(size_t)63;
    const size_t BM_BYTES    = (size_t)BM_WORDS * 4;                 // 2 MB

    if (TABLE_BYTES + IDX_BYTES + BM_BYTES <= ws_size) {
        const unsigned B = 1u << 23;
        int4* table = (int4*)d_ws;
        int* bstart = (int*)((char*)d_ws + TABLE_BYTES);
        unsigned* bitmap = (unsigned*)((char*)d_ws + TABLE_BYTES + IDX_BYTES);
        block_index_kernel<<<(NBLK + 1 + tb - 1) / tb, tb, 0, stream>>>(keys, K, bstart);
        build_rank_kernel<<<NBLK, tb, 0, stream>>>(keys, vals, K, bstart, table,
                                                   bitmap);
        int nthreads = (N >> 2) + 1;  // 4-query groups + tail thread
        lookup_bm_kernel<<<(nthreads + tb - 1) / tb, tb, 0, stream>>>(
            query, keys, vals, table, bitmap, out, N, K, B - 1);
    } else if (TABLE_BYTES <= ws_size) {
        const unsigned B = 1u << 23;
        int4* table = (int4*)d_ws;
        int* bstart = (TABLE_BYTES + (size_t)(NBLK + 1) * 4 <= ws_size)
                          ? (int*)((char*)d_ws + TABLE_BYTES)
                          : (int*)d_out;  // legal scratch: lookup overwrites out
        unsigned* bitmap = (unsigned*)d_out;  // scratch; lookup overwrites out
        block_index_kernel<<<(NBLK + 1 + tb - 1) / tb, tb, 0, stream>>>(keys, K, bstart);
        build_rank_kernel<<<NBLK, tb, 0, stream>>>(keys, vals, K, bstart, table,
                                                   bitmap);
        int half = (N + 1) >> 1;
        lookup_packed_kernel<<<(half + tb - 1) / tb, tb, 0, stream>>>(
            query, keys, vals, table, out, N, K, B - 1);
    } else {
        lookup_bsearch_kernel<<<(N + tb - 1) / tb, tb, 0, stream>>>(query, keys,
                                                                    vals, out, N, K);
    }
}

// Round 17
// 134.130 us; speedup vs baseline: 1.0566x; 1.0328x over previous
//
#include <hip/hip_runtime.h>

// Exact-match lookup of 4M int32 queries in a sorted 8M int32 key table.
// FINAL (round-12 configuration, best measured: 134.4 us total).
// Pipeline: index -> fused rank-scatter build+bitmap -> bitmap-filtered
// packed lookup (4 independent probe chains/thread).
//
// Measured-wall accounting (rocprof, rounds 8-16):
//   lookup: 82.5 us, FETCH 243 MB = 1.00 64B-line/probing-query + ~38 MB
//           bitmap re-fetch, at 3.2-3.3 TB/s == the random-line service wall
//           (independently measured in rounds 1/2/5/8). nt probes lose L3
//           (-20%, r10); sc1 probes read stale data (r13); extra MLP is
//           neutral (r14).
//   build : ~46 us for 194 MB mixed R/W (4-pass rank-scatter; single-pass
//           and nt-store variants both regressed, r15/r16).
//   index : ~3 us.
//
// Table: B = 2^23 buckets (bucket = (unsigned)key >> 8), 16 B/bucket = 128 MB.
// Entry = 4 x 32-bit slots; keys in a bucket share bits [30:8]:
//   bits[31:28] flags: 0=empty, 1=valid pair, 2=overflow descriptor (word0)
//   bits[27:8]  value (build verifies 0 <= val < 2^20, else overflow)
//   bits[7:0]   low 8 bits of key
// Overflow (count>4 or value out of range): word0 = 2<<28, word1 = start
// index into keys/vals; lookup scans forward with early exit on key >= q.
// Slots filled in sorted order, checked in order -> searchsorted-left.
// Queries are >= 1 so empty slots (0) never false-match.
//
// Bitmap: bit b = "some key has key>>7 == b" (2^24 bits = 2 MB). Bit clear ->
// query absent -> skip the table probe (~61% of misses skip). Built with LDS
// atomicOr (commutative -> deterministic) + one 64B line store per block.

constexpr int WCAP     = 1024;     // LDS window capacity per 256-bucket block
constexpr int NBLK     = 1 << 15;  // 32768 build blocks (256 buckets each)
constexpr int BM_WORDS = 1 << 19;  // 2^24 bits / 32 = 512K words = 2 MB

typedef int vint4 __attribute__((ext_vector_type(4)));

__device__ __forceinline__ int lower_bound_u(const int* __restrict__ keys,
                                             int lo, int hi, unsigned t) {
    while (lo < hi) {
        int m = (lo + hi) >> 1;
        if ((unsigned)keys[m] < t) lo = m + 1; else hi = m;
    }
    return lo;
}

// K1: bstart[i] = lower_bound(keys, (i*256)<<8), i in [0, NBLK] inclusive.
__global__ void block_index_kernel(const int* __restrict__ keys, int K,
                                   int* __restrict__ bstart) {
    int i = blockIdx.x * blockDim.x + threadIdx.x;
    if (i > NBLK) return;
    bstart[i] = lower_bound_u(keys, 0, K, ((unsigned)i) << 16);
}

// K2: rank-scatter build + fused bitmap. One block = 256 buckets = 16 bitmap
// words (exactly one 64B bitmap line per block).
__global__ void __launch_bounds__(256) build_rank_kernel(
        const int* __restrict__ keys, const int* __restrict__ vals, int K,
        const int* __restrict__ bstart, int4* __restrict__ table,
        unsigned* __restrict__ bitmap) {
    __shared__ int s_keys[WCAP];
    __shared__ int s_vals[WCAP];
    __shared__ int s_first[256];
    __shared__ int s_flag[256];
    __shared__ int s_ent[256][4];
    __shared__ unsigned s_bm[16];

    const int tid = threadIdx.x;
    const int wlo = bstart[blockIdx.x];
    const int whi = bstart[blockIdx.x + 1];
    const int wn = whi - wlo;
    const unsigned base_b = (unsigned)blockIdx.x << 8;

    s_flag[tid] = 0;
    s_ent[tid][0] = 0; s_ent[tid][1] = 0; s_ent[tid][2] = 0; s_ent[tid][3] = 0;
    if (tid < 16) s_bm[tid] = 0u;

    if (wn <= WCAP) {
        for (int j = tid; j < wn; j += 256) {
            s_keys[j] = keys[wlo + j];
            s_vals[j] = vals[wlo + j];
        }
        __syncthreads();
        // pass B: bucket-first marks (unique writer) + bitmap bits (atomicOr)
        for (int j = tid; j < wn; j += 256) {
            unsigned k = (unsigned)s_keys[j];
            unsigned b = k >> 8;
            bool first = (j == 0) || ((((unsigned)s_keys[j - 1]) >> 8) != b);
            if (first) s_first[b & 255u] = j;
            atomicOr(&s_bm[(k >> 12) & 15u], 1u << ((k >> 7) & 31u));
        }
        __syncthreads();
        // pass C: rank-scatter packed words (unique (bucket,rank) writer)
        for (int j = tid; j < wn; j += 256) {
            int k = s_keys[j];
            unsigned lb = (((unsigned)k) >> 8) & 255u;
            int rank = j - s_first[lb];
            int v = s_vals[j];
            if (rank < 4 && (unsigned)v <= 0xFFFFFu) {
                s_ent[lb][rank] = (1 << 28) | (v << 8) | (k & 0xFF);
            } else {
                s_flag[lb] = 1;  // benign same-value multi-writer
            }
        }
        __syncthreads();
        // pass D: emit table slice (coalesced 16B stores) + bitmap line
        int4 e;
        if (s_flag[tid]) e = make_int4(2 << 28, wlo + s_first[tid], 0, 0);
        else             e = make_int4(s_ent[tid][0], s_ent[tid][1],
                                       s_ent[tid][2], s_ent[tid][3]);
        table[base_b + tid] = e;
        if (tid < 16) bitmap[(unsigned)blockIdx.x * 16u + tid] = s_bm[tid];
    } else {
        // statistically-never fallback: window too big for LDS.
        __syncthreads();
        unsigned b = base_b + tid;
        unsigned tlo = b << 8;
        unsigned thi = tlo + 256u;
        int lo = lower_bound_u(keys, wlo, whi, tlo);
        int w[4] = {0, 0, 0, 0};
        bool ok = true;
        int cnt = 0;
        int j = lo;
        while (j < whi && (unsigned)keys[j] < thi) {
            if (cnt >= 4) { ok = false; break; }
            int v = vals[j];
            if ((unsigned)v > 0xFFFFFu) { ok = false; break; }
            w[cnt] = (1 << 28) | (v << 8) | (keys[j] & 0xFF);
            ++cnt; ++j;
        }
        table[b] = ok ? make_int4(w[0], w[1], w[2], w[3])
                      : make_int4(2 << 28, lo, 0, 0);
        if (tid < 16) {  // bitmap words from global window (correct, slow)
            unsigned w0 = (unsigned)blockIdx.x * 16u + tid;
            unsigned t0 = w0 << 12, t1 = t0 + 4096u;
            int l = lower_bound_u(keys, wlo, whi, t0);
            unsigned word = 0;
            for (int jj = l; jj < whi; ++jj) {
                unsigned k = (unsigned)keys[jj];
                if (k >= t1) break;
                word |= 1u << ((k >> 7) & 31u);
            }
            bitmap[w0] = word;
        }
    }
}

__device__ __forceinline__ int resolve_packed(int q, int4 e,
                                              const int* __restrict__ keys,
                                              const int* __restrict__ vals,
                                              int K) {
    if ((((unsigned)e.x) >> 28) == 2u) {  // overflow: scan original arrays
        for (int j = e.y; j < K; ++j) {
            int k = keys[j];
            if ((unsigned)k >= (unsigned)q) return (k == q) ? vals[j] : -1;
        }
        return -1;
    }
    int ql = q & 0xFF;
    int w;
    w = e.x; if ((((unsigned)w) >> 28) == 1u && (w & 0xFF) == ql) return (w >> 8) & 0xFFFFF;
    w = e.y; if ((((unsigned)w) >> 28) == 1u && (w & 0xFF) == ql) return (w >> 8) & 0xFFFFF;
    w = e.z; if ((((unsigned)w) >> 28) == 1u && (w & 0xFF) == ql) return (w >> 8) & 0xFFFFF;
    w = e.w; if ((((unsigned)w) >> 28) == 1u && (w & 0xFF) == ql) return (w >> 8) & 0xFFFFF;
    return -1;
}

// K3: bitmap-filtered lookup — 4 independent probe chains per thread.
// query/out nt (pure streams); table/bitmap cached (L2/L3 resident).
__global__ void lookup_bm_kernel(const int* __restrict__ query,
                                 const int* __restrict__ keys,
                                 const int* __restrict__ vals,
                                 const int4* __restrict__ table,
                                 const unsigned* __restrict__ bitmap,
                                 int* __restrict__ out,
                                 int N, int K, unsigned Bmask) {
    int nq4 = N >> 2;  // full 4-query groups
    int i = blockIdx.x * blockDim.x + threadIdx.x;
    if (i < nq4) {
        vint4 qv = __builtin_nontemporal_load(
            reinterpret_cast<const vint4*>(query) + i);
        int q[4] = {qv.x, qv.y, qv.z, qv.w};
        unsigned wbits[4];
#pragma unroll
        for (int c = 0; c < 4; ++c) wbits[c] = bitmap[((unsigned)q[c]) >> 12];
        bool probe[4];
        int4 e[4];
#pragma unroll
        for (int c = 0; c < 4; ++c) {
            probe[c] = ((wbits[c] >> ((((unsigned)q[c]) >> 7) & 31u)) & 1u) != 0u;
            e[c] = probe[c] ? table[(((unsigned)q[c]) >> 8) & Bmask]
                            : make_int4(0, 0, 0, 0);
        }
        vint4 r;
        r.x = probe[0] ? resolve_packed(q[0], e[0], keys, vals, K) : -1;
        r.y = probe[1] ? resolve_packed(q[1], e[1], keys, vals, K) : -1;
        r.z = probe[2] ? resolve_packed(q[2], e[2], keys, vals, K) : -1;
        r.w = probe[3] ? resolve_packed(q[3], e[3], keys, vals, K) : -1;
        __builtin_nontemporal_store(r, reinterpret_cast<vint4*>(out) + i);
    } else if (i == nq4) {
        // tail (N % 4 queries), single thread, plain cached path
        for (int j = nq4 * 4; j < N; ++j) {
            int q = query[j];
            unsigned wb = bitmap[((unsigned)q) >> 12];
            bool probe = ((wb >> ((((unsigned)q) >> 7) & 31u)) & 1u) != 0u;
            int r = -1;
            if (probe) {
                int4 e = table[(((unsigned)q) >> 8) & Bmask];
                r = resolve_packed(q, e, keys, vals, K);
            }
            out[j] = r;
        }
    }
}

// K3 alt: no-bitmap lookup (2 probe chains) for smaller workspaces.
__global__ void lookup_packed_kernel(const int* __restrict__ query,
                                     const int* __restrict__ keys,
                                     const int* __restrict__ vals,
                                     const int4* __restrict__ table,
                                     int* __restrict__ out,
                                     int N, int K, unsigned Bmask) {
    int half = (N + 1) >> 1;
    int i = blockIdx.x * blockDim.x + threadIdx.x;
    if (i >= half) return;
    int i1 = i + half;
    bool has1 = (i1 < N);
    int q0 = query[i];
    int q1 = has1 ? query[i1] : q0;
    int4 e0 = table[(((unsigned)q0) >> 8) & Bmask];
    int4 e1 = table[(((unsigned)q1) >> 8) & Bmask];
    out[i] = resolve_packed(q0, e0, keys, vals, K);
    if (has1) out[i1] = resolve_packed(q1, e1, keys, vals, K);
}

// Fallback for tiny workspace: plain binary search (searchsorted 'left').
__global__ void lookup_bsearch_kernel(const int* __restrict__ query,
                                      const int* __restrict__ keys,
                                      const int* __restrict__ vals,
                                      int* __restrict__ out,
                                      int N, int K) {
    int i = blockIdx.x * blockDim.x + threadIdx.x;
    if (i >= N) return;
    unsigned q = (unsigned)query[i];
    int lo = lower_bound_u(keys, 0, K, q);
    int r = -1;
    if (lo < K && (unsigned)keys[lo] == q) r = vals[lo];
    out[i] = r;
}

extern "C" void kernel_launch(void* const* d_in, const int* in_sizes, int n_in,
                              void* d_out, int out_size, void* d_ws, size_t ws_size,
                              hipStream_t stream) {
    const int* query = (const int*)d_in[0];
    const int* keys  = (const int*)d_in[1];
    const int* vals  = (const int*)d_in[2];
    int* out = (int*)d_out;
    const int N = in_sizes[0];
    const int K = in_sizes[1];
    const int tb = 256;

    const size_t TABLE_BYTES = (size_t)16 << 23;                     // 128 MB
    const size_t IDX_BYTES   = (((size_t)(NBLK + 1) * 4) + 63) & ~(size_t)63;
    const size_t BM_BYTES    = (size_t)BM_WORDS * 4;                 // 2 MB

    if (TABLE_BYTES + IDX_BYTES + BM_BYTES <= ws_size) {
        const unsigned B = 1u << 23;
        int4* table = (int4*)d_ws;
        int* bstart = (int*)((char*)d_ws + TABLE_BYTES);
        unsigned* bitmap = (unsigned*)((char*)d_ws + TABLE_BYTES + IDX_BYTES);
        block_index_kernel<<<(NBLK + 1 + tb - 1) / tb, tb, 0, stream>>>(keys, K, bstart);
        build_rank_kernel<<<NBLK, tb, 0, stream>>>(keys, vals, K, bstart, table,
                                                   bitmap);
        int nthreads = (N >> 2) + 1;  // 4-query groups + tail thread
        lookup_bm_kernel<<<(nthreads + tb - 1) / tb, tb, 0, stream>>>(
            query, keys, vals, table, bitmap, out, N, K, B - 1);
    } else if (TABLE_BYTES <= ws_size) {
        const unsigned B = 1u << 23;
        int4* table = (int4*)d_ws;
        int* bstart = (TABLE_BYTES + (size_t)(NBLK + 1) * 4 <= ws_size)
                          ? (int*)((char*)d_ws + TABLE_BYTES)
                          : (int*)d_out;  // legal scratch: lookup overwrites out
        unsigned* bitmap = (unsigned*)d_out;  // scratch; lookup overwrites out
        block_index_kernel<<<(NBLK + 1 + tb - 1) / tb, tb, 0, stream>>>(keys, K, bstart);
        build_rank_kernel<<<NBLK, tb, 0, stream>>>(keys, vals, K, bstart, table,
                                                   bitmap);
        int half = (N + 1) >> 1;
        lookup_packed_kernel<<<(half + tb - 1) / tb, tb, 0, stream>>>(
            query, keys, vals, table, out, N, K, B - 1);
    } else {
        lookup_bsearch_kernel<<<(N + tb - 1) / tb, tb, 0, stream>>>(query, keys,
                                                                    vals, out, N, K);
    }
}